// Round 7
// baseline (4216.594 us; speedup 1.0000x reference)
//
#include <hip/hip_runtime.h>

// VectorQuantizer: z (32,256,32,32) f32, embedding (1024,256) f32.
// N=32768 rows (n = b*1024 + h*32 + w), D=256, K=1024.
// Out (f32, concat): z_q_st [8388608] (B,C,H,W), vq_loss [1], idx [32768].
// z_flat[n][c] = z[b*262144 + c*1024 + (n & 1023)]
//
// v3: occupancy-fixed split GEMM.
//  distK: 2048 blocks (512 row-groups x 4 code-quarters), 64 rows x 256 codes,
//         8x8 acc/thread, d-chunks of 16, double-buffered LDS (40KB, 1 barrier
//         per chunk), reg-staged global prefetch. Partial (m1,m2,k) -> ws.
//  finishK: merge 4 partials/row (order preserves first-index tie-break),
//         flag gap < TAU, np-f32 bit-exact re-derivation (unchanged from the
//         passing r5/r6 kernel), outputs + loss.
// ws: [0] loss f64; [64) enorm[1024]; [4352) eT[256][1024] (1MB);
//     [1052928) pm1[4][32768]; [1577216) pm2; [2101504) pk.

#define TAU 4.0e-4f

__device__ __forceinline__ float np_pairwise256_sq(const float* a) {
  float tot = 0.0f;
#pragma unroll
  for (int blk = 0; blk < 2; ++blk) {
    const float* p = a + blk * 128;
    float r[8];
#pragma unroll
    for (int j = 0; j < 8; ++j) r[j] = __fmul_rn(p[j], p[j]);
    for (int i = 8; i < 128; i += 8) {
#pragma unroll
      for (int j = 0; j < 8; ++j) r[j] = __fadd_rn(r[j], __fmul_rn(p[i + j], p[i + j]));
    }
    float res = __fadd_rn(__fadd_rn(__fadd_rn(r[0], r[1]), __fadd_rn(r[2], r[3])),
                          __fadd_rn(__fadd_rn(r[4], r[5]), __fadd_rn(r[6], r[7])));
    tot = (blk == 0) ? res : __fadd_rn(tot, res);
  }
  return tot;
}

__global__ void initK(double* loss_sum) { *loss_sum = 0.0; }

__global__ __launch_bounds__(256) void enormK(const float* __restrict__ emb,
                                              float* __restrict__ enorm) {
  const int k = blockIdx.x * 256 + threadIdx.x;
  enorm[k] = np_pairwise256_sq(emb + (size_t)k * 256);
}

// eT[d][k] = emb[k][d], 32x32 LDS-tiled transpose.
__global__ __launch_bounds__(256) void transK(const float* __restrict__ emb,
                                              float* __restrict__ eT) {
  __shared__ float t[32][33];
  const int k0 = blockIdx.x * 32, d0 = blockIdx.y * 32;
  const int lx = threadIdx.x & 31, ly = threadIdx.x >> 5;
#pragma unroll
  for (int r = 0; r < 4; ++r)
    t[ly + r * 8][lx] = emb[(size_t)(k0 + ly + r * 8) * 256 + d0 + lx];
  __syncthreads();
#pragma unroll
  for (int r = 0; r < 4; ++r)
    eT[(size_t)(d0 + ly + r * 8) * 1024 + k0 + lx] = t[lx][ly + r * 8];
}

// Distance partial-argmin: block = 64 rows x 256 codes (quarter kq).
__global__ __launch_bounds__(256, 4) void distK(const float* __restrict__ z,
                                                const float* __restrict__ eT,
                                                const float* __restrict__ enorm,
                                                float* __restrict__ pm1,
                                                float* __restrict__ pm2,
                                                int* __restrict__ pk) {
  __shared__ float zl[2 * 16 * 64];    // 8 KB
  __shared__ float el[2 * 16 * 256];   // 32 KB
  const int tid = threadIdx.x;
  const int tx = tid & 31;   // codes
  const int ty = tid >> 5;   // rows
  const int rg = blockIdx.x >> 2;
  const int kq = blockIdx.x & 3;
  const int n0 = rg * 64;
  const int b = n0 >> 10;
  const int hw0 = n0 & 1023;
  const float* zbase = z + (size_t)b * 262144 + hw0;
  const float* ebase = eT + kq * 256;

  const int zd = tid >> 4, zm = (tid & 15) * 4;  // staging coords (z)
  float4 sz, se[4];
  // chunk 0 -> regs -> buf0
  sz = *(const float4*)(zbase + (size_t)zd * 1024 + zm);
#pragma unroll
  for (int r = 0; r < 4; ++r) {
    int idx = r * 256 + tid;
    se[r] = *(const float4*)(ebase + (size_t)(idx >> 6) * 1024 + (idx & 63) * 4);
  }
  *(float4*)(zl + zd * 64 + zm) = sz;
#pragma unroll
  for (int r = 0; r < 4; ++r) {
    int idx = r * 256 + tid;
    *(float4*)(el + (idx >> 6) * 256 + (idx & 63) * 4) = se[r];
  }
  __syncthreads();

  float acc[2][4][2][4];
#pragma unroll
  for (int a = 0; a < 2; ++a)
#pragma unroll
    for (int i = 0; i < 4; ++i)
#pragma unroll
      for (int bb = 0; bb < 2; ++bb)
#pragma unroll
        for (int j = 0; j < 4; ++j) acc[a][i][bb][j] = 0.0f;

  for (int c = 0; c < 16; ++c) {
    const int cur = c & 1;
    if (c < 15) {  // prefetch chunk c+1 into regs (hides under FMA)
      int dd = (c + 1) * 16;
      sz = *(const float4*)(zbase + (size_t)(dd + zd) * 1024 + zm);
#pragma unroll
      for (int r = 0; r < 4; ++r) {
        int idx = r * 256 + tid;
        se[r] = *(const float4*)(ebase + (size_t)(dd + (idx >> 6)) * 1024 + (idx & 63) * 4);
      }
    }
    const float* zc = zl + cur * 1024;
    const float* ec = el + cur * 4096;
#pragma unroll
    for (int d = 0; d < 16; ++d) {
      float4 za = *(const float4*)(zc + d * 64 + ty * 4);
      float4 zb2 = *(const float4*)(zc + d * 64 + 32 + ty * 4);
      float4 ea = *(const float4*)(ec + d * 256 + tx * 4);
      float4 eb = *(const float4*)(ec + d * 256 + 128 + tx * 4);
      float zv[2][4] = {{za.x, za.y, za.z, za.w}, {zb2.x, zb2.y, zb2.z, zb2.w}};
      float ev[2][4] = {{ea.x, ea.y, ea.z, ea.w}, {eb.x, eb.y, eb.z, eb.w}};
#pragma unroll
      for (int a = 0; a < 2; ++a)
#pragma unroll
        for (int i = 0; i < 4; ++i)
#pragma unroll
          for (int bb = 0; bb < 2; ++bb)
#pragma unroll
            for (int j = 0; j < 4; ++j) acc[a][i][bb][j] += zv[a][i] * ev[bb][j];
    }
    if (c < 15) {  // write prefetched chunk to other buffer, one barrier
      const int nxt = cur ^ 1;
      *(float4*)(zl + nxt * 1024 + zd * 64 + zm) = sz;
#pragma unroll
      for (int r = 0; r < 4; ++r) {
        int idx = r * 256 + tid;
        *(float4*)(el + nxt * 4096 + (idx >> 6) * 256 + (idx & 63) * 4) = se[r];
      }
      __syncthreads();
    }
  }

  // epilogue: d' = enorm - 2*dot; (min1,min2,idx) per row; shfl-reduce over tx
  float4 e0 = *(const float4*)(enorm + kq * 256 + tx * 4);
  float4 e1 = *(const float4*)(enorm + kq * 256 + 128 + tx * 4);
  float env[2][4] = {{e0.x, e0.y, e0.z, e0.w}, {e1.x, e1.y, e1.z, e1.w}};
#pragma unroll
  for (int a = 0; a < 2; ++a)
#pragma unroll
    for (int i = 0; i < 4; ++i) {
      float m1 = 3.0e38f, m2 = 3.0e38f;
      int k1 = 0;
#pragma unroll
      for (int bb = 0; bb < 2; ++bb)
#pragma unroll
        for (int j = 0; j < 4; ++j) {
          float v = env[bb][j] - 2.0f * acc[a][i][bb][j];
          int kg = kq * 256 + bb * 128 + tx * 4 + j;
          if (v < m1) { m2 = m1; m1 = v; k1 = kg; }
          else if (v < m2) { m2 = v; }
        }
#pragma unroll
      for (int mask = 1; mask < 32; mask <<= 1) {
        float b1 = __shfl_xor(m1, mask);
        float b2 = __shfl_xor(m2, mask);
        int bi_ = __shfl_xor(k1, mask);
        if (b1 < m1 || (b1 == m1 && bi_ < k1)) { m2 = fminf(m1, b2); m1 = b1; k1 = bi_; }
        else { m2 = fminf(m2, b1); }
      }
      if (tx == 0) {
        int n = n0 + a * 32 + ty * 4 + i;
        pm1[kq * 32768 + n] = m1;
        pm2[kq * 32768 + n] = m2;
        pk[kq * 32768 + n] = k1;
      }
    }
}

// Merge partials + refine + outputs.
__global__ __launch_bounds__(256) void finishK(const float* __restrict__ z,
                                               const float* __restrict__ emb,
                                               const float* __restrict__ enorm,
                                               const float* __restrict__ pm1,
                                               const float* __restrict__ pm2,
                                               const int* __restrict__ pk,
                                               float* __restrict__ out,
                                               double* __restrict__ loss_sum) {
  __shared__ float zrow[256];
  __shared__ int sidx[64];
  __shared__ unsigned long long sflag;
  __shared__ float swv[4];
  __shared__ int swi[4];
  __shared__ double sloss[4];

  const int tid = threadIdx.x;
  const int n0 = blockIdx.x * 64;
  const int b = n0 >> 10;
  const int hw0 = n0 & 1023;
  const float* zbase = z + (size_t)b * 262144 + hw0;

  if (tid == 0) sflag = 0ull;
  if (tid < 64) {  // same wave as init -> ordered
    int n = n0 + tid;
    float a1 = pm1[n], a2 = pm2[n];
    int ai = pk[n];
#pragma unroll
    for (int q = 1; q < 4; ++q) {
      float b1 = pm1[q * 32768 + n], b2 = pm2[q * 32768 + n];
      int bi = pk[q * 32768 + n];
      if (b1 < a1) { a2 = fminf(a1, b2); a1 = b1; ai = bi; }
      else { a2 = fminf(a2, b1); }  // ties: keep earlier (smaller) index
    }
    sidx[tid] = ai;
    if (a2 - a1 < TAU) atomicOr(&sflag, 1ull << tid);
  }
  __syncthreads();

  // ---- np-f32 bit-exact re-derivation for flagged rows ----
  unsigned long long flags = sflag;  // uniform across block
  while (flags) {
    int r = __ffsll(flags) - 1;
    flags &= flags - 1;
    __syncthreads();
    zrow[tid] = z[(size_t)b * 262144 + (size_t)tid * 1024 + hw0 + r];
    __syncthreads();
    float a32 = np_pairwise256_sq(zrow);
    const float* er0 = emb + (size_t)(tid * 4 + 0) * 256;
    const float* er1 = emb + (size_t)(tid * 4 + 1) * 256;
    const float* er2 = emb + (size_t)(tid * 4 + 2) * 256;
    const float* er3 = emb + (size_t)(tid * 4 + 3) * 256;
    float b0 = 0.0f, b1 = 0.0f, b2 = 0.0f, b3 = 0.0f;
    for (int d = 0; d < 256; ++d) {  // BLAS-style sequential FMA chains
      float zv = zrow[d];
      b0 = __fmaf_rn(zv, er0[d], b0);
      b1 = __fmaf_rn(zv, er1[d], b1);
      b2 = __fmaf_rn(zv, er2[d], b2);
      b3 = __fmaf_rn(zv, er3[d], b3);
    }
    float bch[4] = {b0, b1, b2, b3};
    float best = 3.0e38f;
    int bi = 1 << 30;
#pragma unroll
    for (int j = 0; j < 4; ++j) {
      const int k = tid * 4 + j;  // ascending -> first-index wins
      float tb = __fmul_rn(2.0f, bch[j]);
      float d32 = __fadd_rn(__fsub_rn(a32, tb), enorm[k]);
      if (d32 < best) { best = d32; bi = k; }
    }
    for (int mask = 1; mask < 64; mask <<= 1) {
      float ov = __shfl_xor(best, mask);
      int oi = __shfl_xor(bi, mask);
      if (ov < best || (ov == best && oi < bi)) { best = ov; bi = oi; }
    }
    if ((tid & 63) == 0) { swv[tid >> 6] = best; swi[tid >> 6] = bi; }
    __syncthreads();
    if (tid == 0) {
      float bv = swv[0];
      int bix = swi[0];
      for (int q = 1; q < 4; ++q)
        if (swv[q] < bv || (swv[q] == bv && swi[q] < bix)) { bv = swv[q]; bix = swi[q]; }
      sidx[r] = bix;
    }
    __syncthreads();
  }

  // ---- outputs (f32) ----
  if (tid < 64) out[(size_t)8388609 + n0 + tid] = (float)sidx[tid];

  const int m = tid & 63;
  const int cq = tid >> 6;
  const float* erow = emb + (size_t)sidx[m] * 256;
  const size_t zb = (size_t)b * 262144 + hw0 + m;
  double acc2 = 0.0;
  for (int it = 0; it < 64; ++it) {
    int c = it * 4 + cq;
    float zv = zbase[(size_t)c * 1024 + m];
    float zq = erow[c];
    float d = zq - zv;
    out[zb + (size_t)c * 1024] = zv + d;  // z + (z_q - z), f32
    acc2 += (double)(d * d);
  }
  for (int mask = 1; mask < 64; mask <<= 1) acc2 += __shfl_xor(acc2, mask);
  if ((tid & 63) == 0) sloss[tid >> 6] = acc2;
  __syncthreads();
  if (tid == 0)
    atomicAdd(loss_sum, sloss[0] + sloss[1] + sloss[2] + sloss[3]);
}

__global__ void finalK(const double* loss_sum, float* out) {
  double s = *loss_sum;
  out[8388608] = (float)(1.25 * s / 8388608.0);  // (1+beta)*mean, beta=0.25
}

extern "C" void kernel_launch(void* const* d_in, const int* in_sizes, int n_in,
                              void* d_out, int out_size, void* d_ws, size_t ws_size,
                              hipStream_t stream) {
  const float* z = (const float*)d_in[0];
  const float* emb = (const float*)d_in[1];
  float* out = (float*)d_out;
  char* ws = (char*)d_ws;
  double* loss_sum = (double*)ws;
  float* enorm = (float*)(ws + 64);
  float* eT = (float*)(ws + 4352);        // 256x1024 f32 = 1 MB
  float* pm1 = (float*)(ws + 1052928);    // 4x32768 f32
  float* pm2 = (float*)(ws + 1577216);
  int* pk = (int*)(ws + 2101504);

  initK<<<1, 1, 0, stream>>>(loss_sum);
  enormK<<<4, 256, 0, stream>>>(emb, enorm);
  transK<<<dim3(32, 8), 256, 0, stream>>>(emb, eT);
  distK<<<2048, 256, 0, stream>>>(z, eT, enorm, pm1, pm2, pk);
  finishK<<<512, 256, 0, stream>>>(z, emb, enorm, pm1, pm2, pk, out, loss_sum);
  finalK<<<1, 1, 0, stream>>>(loss_sum, out);
}

// Round 8
// 652.424 us; speedup vs baseline: 6.4630x; 6.4630x over previous
//
#include <hip/hip_runtime.h>

// VectorQuantizer: z (32,256,32,32) f32, embedding (1024,256) f32.
// N=32768 rows (n = b*1024 + h*32 + w), D=256, K=1024.
// Out (f32, concat): z_q_st [8388608] (B,C,H,W), vq_loss [1], idx [32768].
// z_flat[n][c] = z[b*262144 + c*1024 + (n & 1023)]
//
// v4 = v3 with the VGPR-cap bug fixed: distK uses plain __launch_bounds__(256).
//  (v3's (256,4) capped VGPRs at 64 -> 15GB scratch spill -> 4ms. rocprof:
//   VGPR_Count=64, WRITE_SIZE 9.6GB. Occupancy is LDS-limited anyway.)
//  distK: 2048 blocks (512 row-groups x 4 code-quarters), 64 rows x 256 codes,
//         8x8 acc/thread, d-chunks of 16, double-buffered LDS (40KB, 1 barrier
//         per chunk), reg-staged global prefetch. Partial (m1,m2,k) -> ws.
//  finishK: merge 4 partials/row (order preserves first-index tie-break),
//         flag gap < TAU, np-f32 bit-exact re-derivation, outputs + loss.
// ws: [0] loss f64; [64) enorm[1024]; [4352) eT[256][1024] (1MB);
//     [1052928) pm1[4][32768]; [1577216) pm2; [2101504) pk.

#define TAU 4.0e-4f

__device__ __forceinline__ float np_pairwise256_sq(const float* a) {
  float tot = 0.0f;
#pragma unroll
  for (int blk = 0; blk < 2; ++blk) {
    const float* p = a + blk * 128;
    float r[8];
#pragma unroll
    for (int j = 0; j < 8; ++j) r[j] = __fmul_rn(p[j], p[j]);
    for (int i = 8; i < 128; i += 8) {
#pragma unroll
      for (int j = 0; j < 8; ++j) r[j] = __fadd_rn(r[j], __fmul_rn(p[i + j], p[i + j]));
    }
    float res = __fadd_rn(__fadd_rn(__fadd_rn(r[0], r[1]), __fadd_rn(r[2], r[3])),
                          __fadd_rn(__fadd_rn(r[4], r[5]), __fadd_rn(r[6], r[7])));
    tot = (blk == 0) ? res : __fadd_rn(tot, res);
  }
  return tot;
}

__global__ void initK(double* loss_sum) { *loss_sum = 0.0; }

__global__ __launch_bounds__(256) void enormK(const float* __restrict__ emb,
                                              float* __restrict__ enorm) {
  const int k = blockIdx.x * 256 + threadIdx.x;
  enorm[k] = np_pairwise256_sq(emb + (size_t)k * 256);
}

// eT[d][k] = emb[k][d], 32x32 LDS-tiled transpose.
__global__ __launch_bounds__(256) void transK(const float* __restrict__ emb,
                                              float* __restrict__ eT) {
  __shared__ float t[32][33];
  const int k0 = blockIdx.x * 32, d0 = blockIdx.y * 32;
  const int lx = threadIdx.x & 31, ly = threadIdx.x >> 5;
#pragma unroll
  for (int r = 0; r < 4; ++r)
    t[ly + r * 8][lx] = emb[(size_t)(k0 + ly + r * 8) * 256 + d0 + lx];
  __syncthreads();
#pragma unroll
  for (int r = 0; r < 4; ++r)
    eT[(size_t)(d0 + ly + r * 8) * 1024 + k0 + lx] = t[lx][ly + r * 8];
}

// Distance partial-argmin: block = 64 rows x 256 codes (quarter kq).
__global__ __launch_bounds__(256) void distK(const float* __restrict__ z,
                                             const float* __restrict__ eT,
                                             const float* __restrict__ enorm,
                                             float* __restrict__ pm1,
                                             float* __restrict__ pm2,
                                             int* __restrict__ pk) {
  __shared__ float zl[2 * 16 * 64];    // 8 KB
  __shared__ float el[2 * 16 * 256];   // 32 KB
  const int tid = threadIdx.x;
  const int tx = tid & 31;   // codes
  const int ty = tid >> 5;   // rows
  const int rg = blockIdx.x >> 2;
  const int kq = blockIdx.x & 3;
  const int n0 = rg * 64;
  const int b = n0 >> 10;
  const int hw0 = n0 & 1023;
  const float* zbase = z + (size_t)b * 262144 + hw0;
  const float* ebase = eT + kq * 256;

  const int zd = tid >> 4, zm = (tid & 15) * 4;  // staging coords (z)
  float4 sz, se[4];
  // chunk 0 -> regs -> buf0
  sz = *(const float4*)(zbase + (size_t)zd * 1024 + zm);
#pragma unroll
  for (int r = 0; r < 4; ++r) {
    int idx = r * 256 + tid;
    se[r] = *(const float4*)(ebase + (size_t)(idx >> 6) * 1024 + (idx & 63) * 4);
  }
  *(float4*)(zl + zd * 64 + zm) = sz;
#pragma unroll
  for (int r = 0; r < 4; ++r) {
    int idx = r * 256 + tid;
    *(float4*)(el + (idx >> 6) * 256 + (idx & 63) * 4) = se[r];
  }
  __syncthreads();

  float acc[2][4][2][4];
#pragma unroll
  for (int a = 0; a < 2; ++a)
#pragma unroll
    for (int i = 0; i < 4; ++i)
#pragma unroll
      for (int bb = 0; bb < 2; ++bb)
#pragma unroll
        for (int j = 0; j < 4; ++j) acc[a][i][bb][j] = 0.0f;

  for (int c = 0; c < 16; ++c) {
    const int cur = c & 1;
    if (c < 15) {  // prefetch chunk c+1 into regs (hides under FMA)
      int dd = (c + 1) * 16;
      sz = *(const float4*)(zbase + (size_t)(dd + zd) * 1024 + zm);
#pragma unroll
      for (int r = 0; r < 4; ++r) {
        int idx = r * 256 + tid;
        se[r] = *(const float4*)(ebase + (size_t)(dd + (idx >> 6)) * 1024 + (idx & 63) * 4);
      }
    }
    const float* zc = zl + cur * 1024;
    const float* ec = el + cur * 4096;
#pragma unroll
    for (int d = 0; d < 16; ++d) {
      float4 za = *(const float4*)(zc + d * 64 + ty * 4);
      float4 zb2 = *(const float4*)(zc + d * 64 + 32 + ty * 4);
      float4 ea = *(const float4*)(ec + d * 256 + tx * 4);
      float4 eb = *(const float4*)(ec + d * 256 + 128 + tx * 4);
      float zv[2][4] = {{za.x, za.y, za.z, za.w}, {zb2.x, zb2.y, zb2.z, zb2.w}};
      float ev[2][4] = {{ea.x, ea.y, ea.z, ea.w}, {eb.x, eb.y, eb.z, eb.w}};
#pragma unroll
      for (int a = 0; a < 2; ++a)
#pragma unroll
        for (int i = 0; i < 4; ++i)
#pragma unroll
          for (int bb = 0; bb < 2; ++bb)
#pragma unroll
            for (int j = 0; j < 4; ++j) acc[a][i][bb][j] += zv[a][i] * ev[bb][j];
    }
    if (c < 15) {  // write prefetched chunk to other buffer, one barrier
      const int nxt = cur ^ 1;
      *(float4*)(zl + nxt * 1024 + zd * 64 + zm) = sz;
#pragma unroll
      for (int r = 0; r < 4; ++r) {
        int idx = r * 256 + tid;
        *(float4*)(el + nxt * 4096 + (idx >> 6) * 256 + (idx & 63) * 4) = se[r];
      }
      __syncthreads();
    }
  }

  // epilogue: d' = enorm - 2*dot; (min1,min2,idx) per row; shfl-reduce over tx
  float4 e0 = *(const float4*)(enorm + kq * 256 + tx * 4);
  float4 e1 = *(const float4*)(enorm + kq * 256 + 128 + tx * 4);
  float env[2][4] = {{e0.x, e0.y, e0.z, e0.w}, {e1.x, e1.y, e1.z, e1.w}};
#pragma unroll
  for (int a = 0; a < 2; ++a)
#pragma unroll
    for (int i = 0; i < 4; ++i) {
      float m1 = 3.0e38f, m2 = 3.0e38f;
      int k1 = 0;
#pragma unroll
      for (int bb = 0; bb < 2; ++bb)
#pragma unroll
        for (int j = 0; j < 4; ++j) {
          float v = env[bb][j] - 2.0f * acc[a][i][bb][j];
          int kg = kq * 256 + bb * 128 + tx * 4 + j;
          if (v < m1) { m2 = m1; m1 = v; k1 = kg; }
          else if (v < m2) { m2 = v; }
        }
#pragma unroll
      for (int mask = 1; mask < 32; mask <<= 1) {
        float b1 = __shfl_xor(m1, mask);
        float b2 = __shfl_xor(m2, mask);
        int bi_ = __shfl_xor(k1, mask);
        if (b1 < m1 || (b1 == m1 && bi_ < k1)) { m2 = fminf(m1, b2); m1 = b1; k1 = bi_; }
        else { m2 = fminf(m2, b1); }
      }
      if (tx == 0) {
        int n = n0 + a * 32 + ty * 4 + i;
        pm1[kq * 32768 + n] = m1;
        pm2[kq * 32768 + n] = m2;
        pk[kq * 32768 + n] = k1;
      }
    }
}

// Merge partials + refine + outputs.
__global__ __launch_bounds__(256) void finishK(const float* __restrict__ z,
                                               const float* __restrict__ emb,
                                               const float* __restrict__ enorm,
                                               const float* __restrict__ pm1,
                                               const float* __restrict__ pm2,
                                               const int* __restrict__ pk,
                                               float* __restrict__ out,
                                               double* __restrict__ loss_sum) {
  __shared__ float zrow[256];
  __shared__ int sidx[64];
  __shared__ unsigned long long sflag;
  __shared__ float swv[4];
  __shared__ int swi[4];
  __shared__ double sloss[4];

  const int tid = threadIdx.x;
  const int n0 = blockIdx.x * 64;
  const int b = n0 >> 10;
  const int hw0 = n0 & 1023;
  const float* zbase = z + (size_t)b * 262144 + hw0;

  if (tid == 0) sflag = 0ull;
  if (tid < 64) {  // same wave as init -> ordered
    int n = n0 + tid;
    float a1 = pm1[n], a2 = pm2[n];
    int ai = pk[n];
#pragma unroll
    for (int q = 1; q < 4; ++q) {
      float b1 = pm1[q * 32768 + n], b2 = pm2[q * 32768 + n];
      int bi = pk[q * 32768 + n];
      if (b1 < a1) { a2 = fminf(a1, b2); a1 = b1; ai = bi; }
      else { a2 = fminf(a2, b1); }  // ties: keep earlier (smaller) index
    }
    sidx[tid] = ai;
    if (a2 - a1 < TAU) atomicOr(&sflag, 1ull << tid);
  }
  __syncthreads();

  // ---- np-f32 bit-exact re-derivation for flagged rows ----
  unsigned long long flags = sflag;  // uniform across block
  while (flags) {
    int r = __ffsll(flags) - 1;
    flags &= flags - 1;
    __syncthreads();
    zrow[tid] = z[(size_t)b * 262144 + (size_t)tid * 1024 + hw0 + r];
    __syncthreads();
    float a32 = np_pairwise256_sq(zrow);
    const float* er0 = emb + (size_t)(tid * 4 + 0) * 256;
    const float* er1 = emb + (size_t)(tid * 4 + 1) * 256;
    const float* er2 = emb + (size_t)(tid * 4 + 2) * 256;
    const float* er3 = emb + (size_t)(tid * 4 + 3) * 256;
    float b0 = 0.0f, b1 = 0.0f, b2 = 0.0f, b3 = 0.0f;
    for (int d = 0; d < 256; ++d) {  // BLAS-style sequential FMA chains
      float zv = zrow[d];
      b0 = __fmaf_rn(zv, er0[d], b0);
      b1 = __fmaf_rn(zv, er1[d], b1);
      b2 = __fmaf_rn(zv, er2[d], b2);
      b3 = __fmaf_rn(zv, er3[d], b3);
    }
    float bch[4] = {b0, b1, b2, b3};
    float best = 3.0e38f;
    int bi = 1 << 30;
#pragma unroll
    for (int j = 0; j < 4; ++j) {
      const int k = tid * 4 + j;  // ascending -> first-index wins
      float tb = __fmul_rn(2.0f, bch[j]);
      float d32 = __fadd_rn(__fsub_rn(a32, tb), enorm[k]);
      if (d32 < best) { best = d32; bi = k; }
    }
    for (int mask = 1; mask < 64; mask <<= 1) {
      float ov = __shfl_xor(best, mask);
      int oi = __shfl_xor(bi, mask);
      if (ov < best || (ov == best && oi < bi)) { best = ov; bi = oi; }
    }
    if ((tid & 63) == 0) { swv[tid >> 6] = best; swi[tid >> 6] = bi; }
    __syncthreads();
    if (tid == 0) {
      float bv = swv[0];
      int bix = swi[0];
      for (int q = 1; q < 4; ++q)
        if (swv[q] < bv || (swv[q] == bv && swi[q] < bix)) { bv = swv[q]; bix = swi[q]; }
      sidx[r] = bix;
    }
    __syncthreads();
  }

  // ---- outputs (f32) ----
  if (tid < 64) out[(size_t)8388609 + n0 + tid] = (float)sidx[tid];

  const int m = tid & 63;
  const int cq = tid >> 6;
  const float* erow = emb + (size_t)sidx[m] * 256;
  const size_t zb = (size_t)b * 262144 + hw0 + m;
  double acc2 = 0.0;
  for (int it = 0; it < 64; ++it) {
    int c = it * 4 + cq;
    float zv = zbase[(size_t)c * 1024 + m];
    float zq = erow[c];
    float d = zq - zv;
    out[zb + (size_t)c * 1024] = zv + d;  // z + (z_q - z), f32
    acc2 += (double)(d * d);
  }
  for (int mask = 1; mask < 64; mask <<= 1) acc2 += __shfl_xor(acc2, mask);
  if ((tid & 63) == 0) sloss[tid >> 6] = acc2;
  __syncthreads();
  if (tid == 0)
    atomicAdd(loss_sum, sloss[0] + sloss[1] + sloss[2] + sloss[3]);
}

__global__ void finalK(const double* loss_sum, float* out) {
  double s = *loss_sum;
  out[8388608] = (float)(1.25 * s / 8388608.0);  // (1+beta)*mean, beta=0.25
}

extern "C" void kernel_launch(void* const* d_in, const int* in_sizes, int n_in,
                              void* d_out, int out_size, void* d_ws, size_t ws_size,
                              hipStream_t stream) {
  const float* z = (const float*)d_in[0];
  const float* emb = (const float*)d_in[1];
  float* out = (float*)d_out;
  char* ws = (char*)d_ws;
  double* loss_sum = (double*)ws;
  float* enorm = (float*)(ws + 64);
  float* eT = (float*)(ws + 4352);        // 256x1024 f32 = 1 MB
  float* pm1 = (float*)(ws + 1052928);    // 4x32768 f32
  float* pm2 = (float*)(ws + 1577216);
  int* pk = (int*)(ws + 2101504);

  initK<<<1, 1, 0, stream>>>(loss_sum);
  enormK<<<4, 256, 0, stream>>>(emb, enorm);
  transK<<<dim3(32, 8), 256, 0, stream>>>(emb, eT);
  distK<<<2048, 256, 0, stream>>>(z, eT, enorm, pm1, pm2, pk);
  finishK<<<512, 256, 0, stream>>>(z, emb, enorm, pm1, pm2, pk, out, loss_sum);
  finalK<<<1, 1, 0, stream>>>(loss_sum, out);
}

// Round 9
// 314.269 us; speedup vs baseline: 13.4172x; 2.0760x over previous
//
#include <hip/hip_runtime.h>

// VectorQuantizer: z (32,256,32,32) f32, embedding (1024,256) f32.
// N=32768 rows (n = b*1024 + h*32 + w), D=256, K=1024.
// Out (f32, concat): z_q_st [8388608] (B,C,H,W), vq_loss [1], idx [32768].
// z_flat[n][c] = z[b*262144 + c*1024 + (n & 1023)]
//
// v5: MFMA distance pass via 2-limb bf16 split (no fp32 MFMA on CDNA4):
//   dot(z,e) ~= zh*eh + zl*eh + zh*el  (3 x mfma_f32_16x16x32_bf16 chains)
//   limb error ~2.4e-5 worst-case << TAU margin; the proven flag(gap<TAU) +
//   np-f32 bit-exact re-derivation (finishK) is unchanged from r5..r8.
// distK: 512 blocks x 4 waves; wave = 16 rows x 1024 codes. A limbs built
//   in-register from z; B limbs fragment-packed in ws by prepBK. No LDS.
// ws: [0] loss f64; [64) enorm[1024]; [4352) B_pack 1MB;
//     [1052928) pm1[32768]; [1184000) pm2; [1315072) pk.

#define TAU 4.0e-4f

typedef __attribute__((ext_vector_type(8))) short short8b;   // 8 bf16
typedef __attribute__((ext_vector_type(4))) float f32x4;

__device__ __forceinline__ unsigned short f2bf_rne(float x) {
  unsigned int u = __float_as_uint(x);
  unsigned int r = u + 0x7fffu + ((u >> 16) & 1u);
  return (unsigned short)(r >> 16);
}
__device__ __forceinline__ float bf2f(unsigned short s) {
  return __uint_as_float(((unsigned int)s) << 16);
}

__device__ __forceinline__ float np_pairwise256_sq(const float* a) {
  float tot = 0.0f;
#pragma unroll
  for (int blk = 0; blk < 2; ++blk) {
    const float* p = a + blk * 128;
    float r[8];
#pragma unroll
    for (int j = 0; j < 8; ++j) r[j] = __fmul_rn(p[j], p[j]);
    for (int i = 8; i < 128; i += 8) {
#pragma unroll
      for (int j = 0; j < 8; ++j) r[j] = __fadd_rn(r[j], __fmul_rn(p[i + j], p[i + j]));
    }
    float res = __fadd_rn(__fadd_rn(__fadd_rn(r[0], r[1]), __fadd_rn(r[2], r[3])),
                          __fadd_rn(__fadd_rn(r[4], r[5]), __fadd_rn(r[6], r[7])));
    tot = (blk == 0) ? res : __fadd_rn(tot, res);
  }
  return tot;
}

__global__ void initK(double* loss_sum) { *loss_sum = 0.0; }

__global__ __launch_bounds__(256) void enormK(const float* __restrict__ emb,
                                              float* __restrict__ enorm) {
  const int k = blockIdx.x * 256 + threadIdx.x;
  enorm[k] = np_pairwise256_sq(emb + (size_t)k * 256);
}

// B_pack: slot ushort-index = ((C*16 + limb*8 + kb)*64 + lane)*8.
// lane = n + 16*s holds e[C*16+n][kb*32 + s*8 + i], limb 0 = eh, 1 = el.
__global__ __launch_bounds__(256) void prepBK(const float* __restrict__ emb,
                                              unsigned short* __restrict__ bp) {
  const int C = blockIdx.x;  // 64 code-blocks of 16
  const int t = threadIdx.x;
  const int n = t & 15, kb = (t >> 4) & 7, limb = t >> 7;
  const float* er = emb + (size_t)(C * 16 + n) * 256 + kb * 32;
#pragma unroll
  for (int s = 0; s < 4; ++s) {
    unsigned int w[4];
#pragma unroll
    for (int p = 0; p < 4; ++p) {
      unsigned short v2[2];
#pragma unroll
      for (int q = 0; q < 2; ++q) {
        float x = er[s * 8 + p * 2 + q];
        unsigned short hi = f2bf_rne(x);
        v2[q] = (limb == 0) ? hi : f2bf_rne(x - bf2f(hi));
      }
      w[p] = (unsigned int)v2[0] | ((unsigned int)v2[1] << 16);
    }
    size_t idx = ((size_t)(C * 16 + limb * 8 + kb) * 64 + (n + 16 * s)) * 8;
    *(uint4*)(bp + idx) = make_uint4(w[0], w[1], w[2], w[3]);
  }
}

// MFMA distance pass: wave = 16 rows x 1024 codes, (min1,min2,idx) -> ws.
__global__ __launch_bounds__(256) void distK(const float* __restrict__ z,
                                             const unsigned short* __restrict__ bp,
                                             const float* __restrict__ enorm,
                                             float* __restrict__ pm1,
                                             float* __restrict__ pm2,
                                             int* __restrict__ pk) {
  const int tid = threadIdx.x;
  const int wid = tid >> 6, lane = tid & 63;
  const int R = blockIdx.x * 4 + wid;  // 2048 row-blocks of 16
  const int n0w = R * 16;
  const int b = n0w >> 10, hw0 = n0w & 1023;
  const int s = lane >> 4, m = lane & 15;
  const float* zb = z + (size_t)b * 262144 + hw0 + m;

  // A limbs in-register: lane holds A[m][k = kb*32 + s*8 + i]
  short8b az[8], al[8];
#pragma unroll
  for (int kb = 0; kb < 8; ++kb) {
    float f[8];
#pragma unroll
    for (int i = 0; i < 8; ++i)
      f[i] = zb[(size_t)(kb * 32 + s * 8 + i) * 1024];
#pragma unroll
    for (int i = 0; i < 8; ++i) {
      unsigned short hi = f2bf_rne(f[i]);
      az[kb][i] = (short)hi;
      al[kb][i] = (short)f2bf_rne(f[i] - bf2f(hi));
    }
  }

  float m1[4], m2[4];
  int k1i[4];
#pragma unroll
  for (int r = 0; r < 4; ++r) { m1[r] = 3.0e38f; m2[r] = 3.0e38f; k1i[r] = 0; }

  short8b be[8], bl[8];
#pragma unroll
  for (int kb = 0; kb < 8; ++kb)  // preload eh(0)
    be[kb] = *(const short8b*)(bp + ((size_t)kb * 64 + lane) * 8);

  for (int nt = 0; nt < 64; ++nt) {
    f32x4 acc = {0.0f, 0.0f, 0.0f, 0.0f};
    float en = enorm[nt * 16 + m];
#pragma unroll
    for (int kb = 0; kb < 8; ++kb)  // zh . eh
      acc = __builtin_amdgcn_mfma_f32_16x16x32_bf16(az[kb], be[kb], acc, 0, 0, 0);
#pragma unroll
    for (int kb = 0; kb < 8; ++kb)  // load el(nt)
      bl[kb] = *(const short8b*)(bp + ((size_t)(nt * 16 + 8 + kb) * 64 + lane) * 8);
#pragma unroll
    for (int kb = 0; kb < 8; ++kb)  // zl . eh
      acc = __builtin_amdgcn_mfma_f32_16x16x32_bf16(al[kb], be[kb], acc, 0, 0, 0);
    if (nt < 63) {
#pragma unroll
      for (int kb = 0; kb < 8; ++kb)  // preload eh(nt+1)
        be[kb] = *(const short8b*)(bp + ((size_t)((nt + 1) * 16 + kb) * 64 + lane) * 8);
    }
#pragma unroll
    for (int kb = 0; kb < 8; ++kb)  // zh . el
      acc = __builtin_amdgcn_mfma_f32_16x16x32_bf16(az[kb], bl[kb], acc, 0, 0, 0);
    const int code = nt * 16 + m;
#pragma unroll
    for (int r = 0; r < 4; ++r) {  // D row = s*4 + r (this lane), col = m
      float v = en - 2.0f * acc[r];
      if (v < m1[r]) { m2[r] = m1[r]; m1[r] = v; k1i[r] = code; }
      else if (v < m2[r]) { m2[r] = v; }
    }
  }

  // reduce over the 16 lanes (same rows, different code-columns)
#pragma unroll
  for (int r = 0; r < 4; ++r) {
    float a1 = m1[r], a2 = m2[r];
    int ai = k1i[r];
#pragma unroll
    for (int mask = 1; mask < 16; mask <<= 1) {
      float b1 = __shfl_xor(a1, mask);
      float b2 = __shfl_xor(a2, mask);
      int bi = __shfl_xor(ai, mask);
      if (b1 < a1 || (b1 == a1 && bi < ai)) { a2 = fminf(a1, b2); a1 = b1; ai = bi; }
      else { a2 = fminf(a2, b1); }
    }
    if (m == 0) {
      int n = n0w + s * 4 + r;
      pm1[n] = a1;
      pm2[n] = a2;
      pk[n] = ai;
    }
  }
}

// Merge + np-f32 bit-exact refine + outputs (proven r5..r8 logic).
__global__ __launch_bounds__(256) void finishK(const float* __restrict__ z,
                                               const float* __restrict__ emb,
                                               const float* __restrict__ enorm,
                                               const float* __restrict__ pm1,
                                               const float* __restrict__ pm2,
                                               const int* __restrict__ pk,
                                               float* __restrict__ out,
                                               double* __restrict__ loss_sum) {
  __shared__ float zrow[256];
  __shared__ int sidx[64];
  __shared__ unsigned long long sflag;
  __shared__ float swv[4];
  __shared__ int swi[4];
  __shared__ double sloss[4];

  const int tid = threadIdx.x;
  const int n0 = blockIdx.x * 64;
  const int b = n0 >> 10;
  const int hw0 = n0 & 1023;
  const float* zbase = z + (size_t)b * 262144 + hw0;

  if (tid == 0) sflag = 0ull;
  if (tid < 64) {  // same wave as init -> ordered
    int n = n0 + tid;
    float a1 = pm1[n], a2 = pm2[n];
    sidx[tid] = pk[n];
    if (a2 - a1 < TAU) atomicOr(&sflag, 1ull << tid);
  }
  __syncthreads();

  unsigned long long flags = sflag;  // uniform across block
  while (flags) {
    int r = __ffsll(flags) - 1;
    flags &= flags - 1;
    __syncthreads();
    zrow[tid] = z[(size_t)b * 262144 + (size_t)tid * 1024 + hw0 + r];
    __syncthreads();
    float a32 = np_pairwise256_sq(zrow);
    const float* er0 = emb + (size_t)(tid * 4 + 0) * 256;
    const float* er1 = emb + (size_t)(tid * 4 + 1) * 256;
    const float* er2 = emb + (size_t)(tid * 4 + 2) * 256;
    const float* er3 = emb + (size_t)(tid * 4 + 3) * 256;
    float b0 = 0.0f, b1 = 0.0f, b2 = 0.0f, b3 = 0.0f;
    for (int d = 0; d < 256; ++d) {  // BLAS-style sequential FMA chains
      float zv = zrow[d];
      b0 = __fmaf_rn(zv, er0[d], b0);
      b1 = __fmaf_rn(zv, er1[d], b1);
      b2 = __fmaf_rn(zv, er2[d], b2);
      b3 = __fmaf_rn(zv, er3[d], b3);
    }
    float bch[4] = {b0, b1, b2, b3};
    float best = 3.0e38f;
    int bi = 1 << 30;
#pragma unroll
    for (int j = 0; j < 4; ++j) {
      const int k = tid * 4 + j;  // ascending -> first-index wins
      float tb = __fmul_rn(2.0f, bch[j]);
      float d32 = __fadd_rn(__fsub_rn(a32, tb), enorm[k]);
      if (d32 < best) { best = d32; bi = k; }
    }
    for (int mask = 1; mask < 64; mask <<= 1) {
      float ov = __shfl_xor(best, mask);
      int oi = __shfl_xor(bi, mask);
      if (ov < best || (ov == best && oi < bi)) { best = ov; bi = oi; }
    }
    if ((tid & 63) == 0) { swv[tid >> 6] = best; swi[tid >> 6] = bi; }
    __syncthreads();
    if (tid == 0) {
      float bv = swv[0];
      int bix = swi[0];
      for (int q = 1; q < 4; ++q)
        if (swv[q] < bv || (swv[q] == bv && swi[q] < bix)) { bv = swv[q]; bix = swi[q]; }
      sidx[r] = bix;
    }
    __syncthreads();
  }

  if (tid < 64) out[(size_t)8388609 + n0 + tid] = (float)sidx[tid];

  const int m = tid & 63;
  const int cq = tid >> 6;
  const float* erow = emb + (size_t)sidx[m] * 256;
  const size_t zb = (size_t)b * 262144 + hw0 + m;
  double acc2 = 0.0;
  for (int it = 0; it < 64; ++it) {
    int c = it * 4 + cq;
    float zv = zbase[(size_t)c * 1024 + m];
    float zq = erow[c];
    float d = zq - zv;
    out[zb + (size_t)c * 1024] = zv + d;  // z + (z_q - z), f32
    acc2 += (double)(d * d);
  }
  for (int mask = 1; mask < 64; mask <<= 1) acc2 += __shfl_xor(acc2, mask);
  if ((tid & 63) == 0) sloss[tid >> 6] = acc2;
  __syncthreads();
  if (tid == 0)
    atomicAdd(loss_sum, sloss[0] + sloss[1] + sloss[2] + sloss[3]);
}

__global__ void finalK(const double* loss_sum, float* out) {
  double s = *loss_sum;
  out[8388608] = (float)(1.25 * s / 8388608.0);  // (1+beta)*mean, beta=0.25
}

extern "C" void kernel_launch(void* const* d_in, const int* in_sizes, int n_in,
                              void* d_out, int out_size, void* d_ws, size_t ws_size,
                              hipStream_t stream) {
  const float* z = (const float*)d_in[0];
  const float* emb = (const float*)d_in[1];
  float* out = (float*)d_out;
  char* ws = (char*)d_ws;
  double* loss_sum = (double*)ws;
  float* enorm = (float*)(ws + 64);
  unsigned short* bp = (unsigned short*)(ws + 4352);  // 1 MB B_pack
  float* pm1 = (float*)(ws + 1052928);
  float* pm2 = (float*)(ws + 1184000);
  int* pk = (int*)(ws + 1315072);

  initK<<<1, 1, 0, stream>>>(loss_sum);
  enormK<<<4, 256, 0, stream>>>(emb, enorm);
  prepBK<<<64, 256, 0, stream>>>(emb, bp);
  distK<<<512, 256, 0, stream>>>(z, bp, enorm, pm1, pm2, pk);
  finishK<<<512, 256, 0, stream>>>(z, emb, enorm, pm1, pm2, pk, out, loss_sum);
  finalK<<<1, 1, 0, stream>>>(loss_sum, out);
}